// Round 13
// baseline (483.942 us; speedup 1.0000x reference)
//
#include <hip/hip_runtime.h>
#include <hip/hip_bf16.h>
#include <stdint.h>

// ---------------------------------------------------------------------------
// FacebookAdaptiveSoftmax forward on MI355X (gfx950) — R13 (MEASUREMENT ROUND)
//   out[4096, 50259] = concat(x@head_w^T, (x@t0w1^T)@t0w2^T * m0, (x@t1w1^T)@t1w2^T * m1)
//   new_head_target[4096] appended flat (as float)
// R13 = R11 VERBATIM (NT stores restored after R12 showed they help ~+50us;
// scan/cast launches un-merged) + gemm_tails launched TWICE.
// The second L3 launch is idempotent (same deterministic values, disjoint
// from fill rows) -> dur_us = R11_dur + L3_dur. This measures L3 directly
// and L2 by subtraction, resolving which launch holds the remaining ~130us
// of slack over the component floor.
// ---------------------------------------------------------------------------

typedef float  f32x4   __attribute__((ext_vector_type(4)));
typedef short  short8  __attribute__((ext_vector_type(8)));
typedef unsigned short ushort8 __attribute__((ext_vector_type(8)));

#define CUT0 10000
#define CUT1 40000
#define CUT2 50257
#define LDC   50259L

__device__ __forceinline__ void gload16(const void* g, void* l) {
    __builtin_amdgcn_global_load_lds(
        (__attribute__((address_space(1))) void*)(g),
        (__attribute__((address_space(3))) void*)(l), 16, 0, 0);
}

__device__ __forceinline__ unsigned short f2bf(float f) {
    unsigned int u = __float_as_uint(f);
    u += 0x7fffu + ((u >> 16) & 1u);   // round-to-nearest-even
    return (unsigned short)(u >> 16);
}

__device__ __forceinline__ short8 dsr128(unsigned addr) {
    f32x4 r;
    asm volatile("ds_read_b128 %0, %1" : "=v"(r) : "v"(addr));
    return __builtin_bit_cast(short8, r);
}

__device__ __forceinline__ f32x4 mfma16(short8 a, short8 b, f32x4 c) {
    return __builtin_amdgcn_mfma_f32_16x16x32_bf16(a, b, c, 0, 0, 0);
}

__device__ __forceinline__ void nt4(float* p, f32x4 v) {
    __builtin_nontemporal_store(v[0], p);
    __builtin_nontemporal_store(v[1], p + 1);
    __builtin_nontemporal_store(v[2], p + 2);
    __builtin_nontemporal_store(v[3], p + 3);
}

// ===========================================================================
// L0: target remap + order-preserving compaction scan (1 block, 1024 thr).
// ===========================================================================
__global__ __launch_bounds__(1024)
void scan_kernel(const int* __restrict__ tgt, float* __restrict__ outT,
                 int* __restrict__ in0, int* __restrict__ z0,
                 int* __restrict__ in1, int* __restrict__ z1,
                 int* __restrict__ cnts) {
    __shared__ int w0[16], w1[16];
    const int t = threadIdx.x;
    int f0[4], f1[4];
    int c0 = 0, c1 = 0;
#pragma unroll
    for (int j = 0; j < 4; ++j) {
        const int r = t * 4 + j;
        const int v = tgt[r];
        const int b0 = (v >= CUT0) && (v < CUT1);
        const int b1 = (v >= CUT1) && (v < CUT2);
        f0[j] = b0; f1[j] = b1;
        c0 += b0; c1 += b1;
        outT[r] = (float)(b0 ? CUT0 : (b1 ? CUT0 + 1 : v));
    }
    const int lane = t & 63, w = t >> 6;
    int s0 = c0, s1 = c1;
    for (int d = 1; d < 64; d <<= 1) {
        const int u0 = __shfl_up(s0, d, 64);
        const int u1 = __shfl_up(s1, d, 64);
        if (lane >= d) { s0 += u0; s1 += u1; }
    }
    if (lane == 63) { w0[w] = s0; w1[w] = s1; }
    __syncthreads();
    if (t == 0) {
        int a0 = 0, a1 = 0;
        for (int i = 0; i < 16; ++i) {
            const int x0 = w0[i]; w0[i] = a0; a0 += x0;
            const int x1 = w1[i]; w1[i] = a1; a1 += x1;
        }
        cnts[0] = a0; cnts[1] = a1;
    }
    __syncthreads();
    int run0 = w0[w] + (s0 - c0);
    int run1 = w1[w] + (s1 - c1);
#pragma unroll
    for (int j = 0; j < 4; ++j) {
        const int r = t * 4 + j;
        if (f0[j]) in0[run0++] = r; else z0[r - run0] = r;
        if (f1[j]) in1[run1++] = r; else z1[r - run1] = r;
    }
}

// ===========================================================================
// L1: fused casts (5 segments, f32 -> bf16, zero row padding).
// ===========================================================================
struct CastSeg {
    const float* srcA;
    const float* srcB;
    unsigned short* dst;
    long rowsA, rowsB, total8;
    int lk, pad;
};
struct CastArgs {
    CastSeg s[5];
    long grand8;
};

__global__ __launch_bounds__(256)
void cast_kernel(CastArgs a) {
    long i = blockIdx.x * 256L + threadIdx.x;
    const long stride = (long)gridDim.x * 256L;
    for (; i < a.grand8; i += stride) {
        long off = i;
        int s = 0;
        while (s < 4 && off >= a.s[s].total8) { off -= a.s[s].total8; s++; }
        const CastSeg& sg = a.s[s];
        const long e   = off << 3;
        const long row = e >> sg.lk;
        ushort8 o;
        const float* src = nullptr;
        long r2 = row;
        if (row < sg.rowsA)      src = sg.srcA;
        else if (row < sg.rowsB) { src = sg.srcB; r2 = row - sg.rowsA; }
        if (src) {
            const long col = e & ((1L << sg.lk) - 1);
            const float* p = src + (r2 << sg.lk) + col;
            const float4 v0 = *(const float4*)(p);
            const float4 v1 = *(const float4*)(p + 4);
            o[0] = f2bf(v0.x); o[1] = f2bf(v0.y); o[2] = f2bf(v0.z); o[3] = f2bf(v0.w);
            o[4] = f2bf(v1.x); o[5] = f2bf(v1.y); o[6] = f2bf(v1.z); o[7] = f2bf(v1.w);
        } else {
            o = (ushort8)0;
        }
        *(ushort8*)(sg.dst + e) = o;
    }
}

// ===========================================================================
// L2: 8-phase 256x256 BK=64 GEMM (head f32-out | h01 bf16-out) + interleaved
// dedicated FILL blocks (zero masked tail rows, NT stores). R11 verbatim.
// ===========================================================================
#define STAGE2(MATP, LDM, RB, KCOL, LOFF)                                          \
    do {                                                                           \
        const unsigned short* _s0 = (MATP) + ((long)((RB) + (tid >> 3))) * (LDM) + (KCOL); \
        gload16(_s0, smem + (LOFF) + wave * 1024);                                 \
        const unsigned short* _s1 = (MATP) + ((long)((RB) + 64 + (tid >> 3))) * (LDM) + (KCOL); \
        gload16(_s1, smem + (LOFF) + 8192 + wave * 1024);                          \
    } while (0)

__global__ __launch_bounds__(512, 2)
void gemm8_dual_kernel(const unsigned short* __restrict__ A0,
                       const unsigned short* __restrict__ B0,
                       float* __restrict__ C0,
                       int nkt0, int lda0, int ldb0, int width0, int NB0, int nblk0,
                       const unsigned short* __restrict__ A1,
                       const unsigned short* __restrict__ B1,
                       unsigned short* __restrict__ C1,
                       int nkt1, int lda1, int ldb1, long ldc1, int width1, int NB1,
                       const int* __restrict__ z0, const int* __restrict__ z1,
                       const int* __restrict__ cnts, float* __restrict__ outFull) {
    __shared__ char smem[131072];

    const int tid  = threadIdx.x;
    const int lane = tid & 63;
    const int wave = tid >> 6;
    const int wr   = wave >> 2;
    const int wc   = wave & 3;

    // ---- id -> {GEMM gid | fill fidx} (period-10 interleave) ----
    const int pid = blockIdx.x / 10;
    const int pos = blockIdx.x - 10 * pid;
    const bool isGemm = (pos == 0) || (pos == 3) || (pos == 6);

    if (!isGemm) {
        const int fmap = (pos < 3) ? (pos - 1) : (pos < 6 ? pos - 2 : pos - 3);
        const int fidx = pid * 7 + fmap;
        const bool isT0 = fidx < 768;
        const int zc = 4096 - cnts[isT0 ? 0 : 1];
        const int* zl = isT0 ? z0 : z1;
        float* base0 = outFull + (isT0 ? 10002 : 40002);
        const int width = isT0 ? 30000 : 10257;
        const int fstride = isT0 ? 768 : 800;
        const f32x4 zv = {0.f, 0.f, 0.f, 0.f};
        for (int s = isT0 ? fidx : fidx - 768; s < zc; s += fstride) {
            float* base = base0 + (long)zl[s] * LDC;
            for (int j = tid * 4; j + 3 < width; j += 2048)
                nt4(base + j, zv);
            for (int j = (width & ~3) + tid; j < width; j += 512)
                __builtin_nontemporal_store(0.f, base + j);
        }
        return;
    }

    const int gid = pid * 3 + (pos == 0 ? 0 : (pos == 3 ? 1 : 2));
    const bool isHead = gid < nblk0;
    const unsigned short* A = isHead ? A0 : A1;
    const unsigned short* B = isHead ? B0 : B1;
    const int nkt   = isHead ? nkt0 : nkt1;
    const int lda   = isHead ? lda0 : lda1;
    const int ldb   = isHead ? ldb0 : ldb1;
    const int width = isHead ? width0 : width1;
    const int NB    = isHead ? NB0 : NB1;
    const int lbid  = isHead ? gid : gid - nblk0;
    const int nwg   = isHead ? nblk0 : 672 - nblk0;

    const int q = nwg >> 3, r = nwg & 7;
    const int xcd = lbid & 7, loc = lbid >> 3;
    const int L = (xcd < r ? xcd * (q + 1) : r * (q + 1) + (xcd - r) * q) + loc;
    const int g = L / (NB * 4);
    const int t = L - g * (NB * 4);
    const long bm = g * 4 + (t & 3);
    const long bn = t >> 2;

    const long bmRow = bm * 256;
    const long bnRow = bn * 256;

    const int scol = (((tid & 7) ^ ((tid >> 3) & 7)) << 3);

    const unsigned lane15 = lane & 15;
    const unsigned rsw   = (lane15 & 7) << 4;
    const unsigned kcol0 = (((lane >> 4) << 4)) ^ rsw;
    const unsigned kcol1 = (64u + ((lane >> 4) << 4)) ^ rsw;
    const unsigned smemBase =
        (unsigned)(size_t)(__attribute__((address_space(3))) char*)smem;
    const unsigned aB0 = smemBase + wr * 16384 + lane15 * 128;
    const unsigned bB0 = smemBase + 32768 + (wc >> 1) * 16384 +
                         ((wc & 1) * 64 + lane15) * 128;

    f32x4 acc[8][4];
#pragma unroll
    for (int m = 0; m < 8; m++)
#pragma unroll
        for (int n = 0; n < 4; n++) acc[m][n] = (f32x4){0.f, 0.f, 0.f, 0.f};

    STAGE2(A, lda, bmRow,       scol, 0);
    STAGE2(A, lda, bmRow + 128, scol, 16384);
    STAGE2(B, ldb, bnRow,       scol, 32768);
    STAGE2(B, ldb, bnRow + 128, scol, 49152);

    short8 afk0[4], afk1[4], bA0[2], bA1[2], bH0[2], bH1[2];

    for (int kt = 0; kt < nkt; ++kt) {
        const int c  = kt & 1;
        const bool pf = (kt + 1) < nkt;
        const int kc = (kt + 1) * 64 + scol;
        const unsigned aBase = aB0 + c * 65536;
        const unsigned bBase = bB0 + c * 65536;
        const unsigned lOff  = (c ^ 1) * 65536;

        // phase 0 : Q0
        if (pf) {
            STAGE2(A, lda, bmRow, kc, lOff);
            asm volatile("s_waitcnt vmcnt(2)" ::: "memory");
        } else {
            asm volatile("s_waitcnt vmcnt(0)" ::: "memory");
        }
        __builtin_amdgcn_s_barrier();
#pragma unroll
        for (int mf = 0; mf < 4; ++mf) {
            afk0[mf] = dsr128(aBase + mf * 2048 + kcol0);
            afk1[mf] = dsr128(aBase + mf * 2048 + kcol1);
        }
#pragma unroll
        for (int nf = 0; nf < 2; ++nf) {
            bA0[nf] = dsr128(bBase + nf * 2048 + kcol0);
            bA1[nf] = dsr128(bBase + nf * 2048 + kcol1);
        }
        asm volatile("s_waitcnt lgkmcnt(0)" ::: "memory");
        __builtin_amdgcn_sched_barrier(0);
        __builtin_amdgcn_s_setprio(1);
#pragma unroll
        for (int mf = 0; mf < 4; ++mf)
#pragma unroll
            for (int nf = 0; nf < 2; ++nf) {
                acc[mf][nf] = mfma16(bA0[nf], afk0[mf], acc[mf][nf]);
                acc[mf][nf] = mfma16(bA1[nf], afk1[mf], acc[mf][nf]);
            }
        __builtin_amdgcn_s_setprio(0);
        __builtin_amdgcn_s_barrier();

        // phase 1 : Q1
#pragma unroll
        for (int nf = 0; nf < 2; ++nf) {
            bH0[nf] = dsr128(bBase + (2 + nf) * 2048 + kcol0);
            bH1[nf] = dsr128(bBase + (2 + nf) * 2048 + kcol1);
        }
        if (pf) STAGE2(A, lda, bmRow + 128, kc, lOff + 16384);
        __builtin_amdgcn_s_barrier();
        asm volatile("s_waitcnt lgkmcnt(0)" ::: "memory");
        __builtin_amdgcn_sched_barrier(0);
        __builtin_amdgcn_s_setprio(1);
#pragma unroll
        for (int mf = 0; mf < 4; ++mf)
#pragma unroll
            for (int nf = 0; nf < 2; ++nf) {
                acc[mf][2 + nf] = mfma16(bH0[nf], afk0[mf], acc[mf][2 + nf]);
                acc[mf][2 + nf] = mfma16(bH1[nf], afk1[mf], acc[mf][2 + nf]);
            }
        __builtin_amdgcn_s_setprio(0);
        __builtin_amdgcn_s_barrier();

        // phase 2 : Q2
#pragma unroll
        for (int mf = 0; mf < 4; ++mf) {
            afk0[mf] = dsr128(aBase + (4 + mf) * 2048 + kcol0);
            afk1[mf] = dsr128(aBase + (4 + mf) * 2048 + kcol1);
        }
        if (pf) STAGE2(B, ldb, bnRow, kc, lOff + 32768);
        __builtin_amdgcn_s_barrier();
        asm volatile("s_waitcnt lgkmcnt(0)" ::: "memory");
        __builtin_amdgcn_sched_barrier(0);
        __builtin_amdgcn_s_setprio(1);
#pragma unroll
        for (int mf = 0; mf < 4; ++mf)
#pragma unroll
            for (int nf = 0; nf < 2; ++nf) {
                acc[4 + mf][2 + nf] = mfma16(bH0[nf], afk0[mf], acc[4 + mf][2 + nf]);
                acc[4 + mf][2 + nf] = mfma16(bH1[nf], afk1[mf], acc[4 + mf][2 + nf]);
            }
        __builtin_amdgcn_s_setprio(0);
        __builtin_amdgcn_s_barrier();

        // phase 3 : Q3
#pragma unroll
        for (int nf = 0; nf < 2; ++nf) {
            bA0[nf] = dsr128(bBase + nf * 2048 + kcol0);
            bA1[nf] = dsr128(bBase + nf * 2048 + kcol1);
        }
        if (pf) STAGE2(B, ldb, bnRow + 128, kc, lOff + 49152);
        __builtin_amdgcn_s_barrier();
        asm volatile("s_waitcnt lgkmcnt(0)" ::: "memory");
        __builtin_amdgcn_sched_barrier(0);
        __builtin_amdgcn_s_setprio(1);
#pragma unroll
        for (int mf = 0; mf < 4; ++mf)
#pragma unroll
            for (int nf = 0; nf < 2; ++nf) {
                acc[4 + mf][nf] = mfma16(bA0[nf], afk0[mf], acc[4 + mf][nf]);
                acc[4 + mf][nf] = mfma16(bA1[nf], afk1[mf], acc[4 + mf][nf]);
            }
        __builtin_amdgcn_s_setprio(0);
        __builtin_amdgcn_s_barrier();
    }

    const int cb4 = (lane >> 4) << 2;
    if (isHead) {
        // transposed coalesced epilogue: LDS [128][256] f32, 2 passes
        for (int h = 0; h < 2; ++h) {
            __syncthreads();
            if (wr == h) {
#pragma unroll
                for (int mf = 0; mf < 8; ++mf) {
                    const int rl = mf * 16 + (int)lane15;
#pragma unroll
                    for (int nf = 0; nf < 4; ++nf) {
                        const int slot = wc * 16 + nf * 4 + (lane >> 4);
                        const int sl = slot ^ (rl & 7);
                        *(f32x4*)(smem + rl * 1024 + sl * 16) = acc[mf][nf];
                    }
                }
            }
            __syncthreads();
            const int colBase = (int)bnRow + lane * 4;
#pragma unroll
            for (int it = 0; it < 16; ++it) {
                const int rl = wave * 16 + it;
                const int sl = lane ^ (rl & 7);
                const f32x4 v = *(const f32x4*)(smem + rl * 1024 + sl * 16);
                float* rp = C0 + (bmRow + h * 128 + rl) * LDC;
                if (colBase + 3 < width) {
                    __builtin_memcpy(rp + colBase, &v, 16);
                } else {
#pragma unroll
                    for (int j = 0; j < 4; ++j)
                        if (colBase + j < width) rp[colBase + j] = v[j];
                }
            }
        }
    } else {
#pragma unroll
        for (int mf = 0; mf < 8; ++mf) {
            const long grow = bmRow + wr * 128 + mf * 16 + lane15;
            unsigned short* rp = C1 + grow * ldc1;
#pragma unroll
            for (int nf = 0; nf < 4; ++nf) {
                const int gcb = (int)bnRow + wc * 64 + nf * 16 + cb4;
                const f32x4 v = acc[mf][nf];
                ushort4 o;
                o.x = f2bf(v[0]); o.y = f2bf(v[1]); o.z = f2bf(v[2]); o.w = f2bf(v[3]);
                if (gcb + 3 < width) {
                    *(ushort4*)(rp + gcb) = o;
                } else {
                    unsigned short tmp[4] = {o.x, o.y, o.z, o.w};
#pragma unroll
                    for (int j = 0; j < 4; ++j)
                        if (gcb + j < width) rp[gcb + j] = tmp[j];
                }
            }
        }
    }
}

// ===========================================================================
// L3: compacted tails, BK=64, rule-21 swizzled staging/reads, transposed
// coalesced epilogue with NT scalar stores. (R11 verbatim.)
// ===========================================================================
__global__ __launch_bounds__(256)
void gemm_tails_kernel(const unsigned short* __restrict__ A0,
                       const unsigned short* __restrict__ B0,
                       float* __restrict__ C0,
                       int K0, int lda0, int width0, int NB0, int nblk0,
                       const unsigned short* __restrict__ A1,
                       const unsigned short* __restrict__ B1,
                       float* __restrict__ C1,
                       int K1, int lda1, int width1, int NB1,
                       const int* __restrict__ in0,
                       const int* __restrict__ in1,
                       const int* __restrict__ cnts) {
    __shared__ char tsm[32768];

    const int tid  = threadIdx.x;
    const int lane = tid & 63;
    const int wave = tid >> 6;
    const int wr   = wave >> 1;
    const int wc   = wave & 1;

    const bool is0 = (int)blockIdx.x < nblk0;
    const unsigned short* A = is0 ? A0 : A1;
    const unsigned short* B = is0 ? B0 : B1;
    float* Cf               = is0 ? C0 : C1;
    const int* rowlist      = is0 ? in0 : in1;
    const int cnt           = cnts[is0 ? 0 : 1];
    const int K     = is0 ? K0 : K1;
    const int lda   = is0 ? lda0 : lda1;
    const int width = is0 ? width0 : width1;
    const int NB    = is0 ? NB0 : NB1;
    const int lbid  = is0 ? blockIdx.x : blockIdx.x - nblk0;
    const int nwg   = is0 ? nblk0 : (int)gridDim.x - nblk0;

    const int q = nwg >> 3, r = nwg & 7;
    const int xcd = lbid & 7, loc = lbid >> 3;
    const int L = (xcd < r ? xcd * (q + 1) : r * (q + 1) + (xcd - r) * q) + loc;
    const int g = L / (NB << 3);
    const int t = L - g * (NB << 3);
    const long bm = (g << 3) + (t & 7);
    const long bn = t >> 3;

    if ((int)(bm * 128) >= cnt) return;

    const int cm1 = cnt - 1;
    const int s_row = tid >> 3;                          // 0..31
    const int sc    = (((tid & 7) ^ (s_row & 7)) << 3);  // elem col

    int ar[4];
#pragma unroll
    for (int gg = 0; gg < 4; ++gg) {
        const int gi = (int)(bm * 128) + s_row + 32 * gg;
        ar[gg] = rowlist[gi < cnt ? gi : cm1];
    }
    const unsigned short* pB0 = B + (bn * 128 + s_row) * (long)K + sc;

    f32x4 acc[4][4];
#pragma unroll
    for (int m = 0; m < 4; m++)
#pragma unroll
        for (int n = 0; n < 4; n++) acc[m][n] = (f32x4){0.f, 0.f, 0.f, 0.f};

    const int f_r = lane & 15;
    const int fkb = (lane >> 4) << 4;   // byte offset of k-chunk in half

    for (int k0 = 0; k0 < K; k0 += 64) {
#pragma unroll
        for (int gg = 0; gg < 4; ++gg) {
            gload16(A + (long)ar[gg] * lda + sc + k0,
                    tsm + gg * 4096 + wave * 1024);
            gload16(pB0 + (long)(32 * gg) * K + k0,
                    tsm + 16384 + gg * 4096 + wave * 1024);
        }
        __syncthreads();

#pragma unroll
        for (int h = 0; h < 2; ++h) {
            short8 af[4], bfr[4];
#pragma unroll
            for (int m = 0; m < 4; m++) {
                const int row = wr * 64 + m * 16 + f_r;
                const int cb = (h * 64 + fkb) ^ ((row & 7) << 4);
                af[m] = *(const short8*)(tsm + row * 128 + cb);
            }
#pragma unroll
            for (int n = 0; n < 4; n++) {
                const int row = wc * 64 + n * 16 + f_r;
                const int cb = (h * 64 + fkb) ^ ((row & 7) << 4);
                bfr[n] = *(const short8*)(tsm + 16384 + row * 128 + cb);
            }
#pragma unroll
            for (int m = 0; m < 4; m++)
#pragma unroll
                for (int n = 0; n < 4; n++)
                    acc[m][n] = mfma16(bfr[n], af[m], acc[m][n]);
        }
        __syncthreads();
    }

    // ---- transposed coalesced epilogue: LDS [64][128] f32, 2 passes ----
    const int c_a  = lane & 15;
    const int colL = (lane & 31) * 4;
    for (int h = 0; h < 2; ++h) {
        __syncthreads();
        if (wr == h) {
#pragma unroll
            for (int m = 0; m < 4; ++m) {
                const int rl = m * 16 + c_a;
#pragma unroll
                for (int n = 0; n < 4; ++n) {
                    const int slot = wc * 16 + n * 4 + (lane >> 4);
                    const int sl = slot ^ (rl & 7);
                    *(f32x4*)(tsm + rl * 512 + sl * 16) = acc[m][n];
                }
            }
        }
        __syncthreads();
#pragma unroll
        for (int it = 0; it < 8; ++it) {
            const int rl = wave * 16 + it * 2 + (lane >> 5);
            const int gri = (int)(bm * 128) + h * 64 + rl;
            if (gri < cnt) {
                const int sl = (lane & 31) ^ (rl & 7);
                const f32x4 v = *(const f32x4*)(tsm + rl * 512 + sl * 16);
                const long orow = rowlist[gri];
                float* rp = Cf + orow * LDC;
                const int col = (int)(bn * 128) + colL;
                if (col + 3 < width) {
                    nt4(rp + col, v);
                } else {
#pragma unroll
                    for (int j = 0; j < 4; ++j)
                        if (col + j < width)
                            __builtin_nontemporal_store(v[j], rp + col + j);
                }
            }
        }
    }
}

extern "C" void kernel_launch(void* const* d_in, const int* in_sizes, int n_in,
                              void* d_out, int out_size, void* d_ws, size_t ws_size,
                              hipStream_t stream) {
    const float* x      = (const float*)d_in[0];   // [4096,1024]
    const int*   target = (const int*)  d_in[1];   // [4096]
    const float* head_w = (const float*)d_in[2];   // [10002,1024]
    const float* t0_w1  = (const float*)d_in[3];   // [256,1024]
    const float* t0_w2  = (const float*)d_in[4];   // [30000,256]
    const float* t1_w1  = (const float*)d_in[5];   // [64,1024]
    const float* t1_w2  = (const float*)d_in[6];   // [10257,64]
    float* out = (float*)d_out;

    // ---- ws layout (bytes) ----
    char* ws = (char*)d_ws;
    unsigned short* xb    = (unsigned short*)(ws + 0);          // 4096x1024
    unsigned short* hwb   = (unsigned short*)(ws + 8388608);    // 10240x1024
    unsigned short* w01b  = (unsigned short*)(ws + 29360128);   // 512x1024 (t0w1|t1w1|0)
    unsigned short* t0w2b = (unsigned short*)(ws + 30408704);   // 30208x256
    unsigned short* t1w2b = (unsigned short*)(ws + 45875200);   // 10496x64
    unsigned short* h01   = (unsigned short*)(ws + 47218688);   // 4096x384 bf16
    int*            in0   = (int*)(ws + 50364416);              // 4096
    int*            z0l   = (int*)(ws + 50380800);              // 4096
    int*            in1   = (int*)(ws + 50397184);              // 4096
    int*            z1l   = (int*)(ws + 50413568);              // 4096
    int*            cnts  = (int*)(ws + 50429952);              // 2

    // ---- L0: scan (target remap + compaction lists) ----
    scan_kernel<<<1, 1024, 0, stream>>>(target, out + 4096L * LDC,
                                        in0, z0l, in1, z1l, cnts);

    // ---- L1: casts ----
    CastArgs ca;
    ca.s[0] = {x,      nullptr, xb,    4096,  4096,  524288,  10, 0};
    ca.s[1] = {head_w, nullptr, hwb,   10002, 10002, 1310720, 10, 0};
    ca.s[2] = {t0_w1,  t1_w1,   w01b,  256,   320,   65536,   10, 0};
    ca.s[3] = {t0_w2,  nullptr, t0w2b, 30000, 30000, 966656,  8,  0};
    ca.s[4] = {t1_w2,  nullptr, t1w2b, 10257, 10257, 83968,   6,  0};
    ca.grand8 = 524288 + 1310720 + 65536 + 966656 + 83968;  // 2951168
    cast_kernel<<<2048, 256, 0, stream>>>(ca);

    // ---- L2: head (640) + h01 (32) GEMM blocks + 1568 fill blocks ----
    gemm8_dual_kernel<<<dim3(2240), 512, 0, stream>>>(
        xb, hwb, out, 16, 1024, 1024, 10002, 40, 640,
        xb, w01b, h01, 16, 1024, 1024, 384L, 384, 2,
        z0l, z1l, cnts, out);

    // ---- L3: compacted tails (BK=64) — LAUNCHED TWICE (measurement:
    //      idempotent; dur_us - R11_dur = one L3 duration) ----
    gemm_tails_kernel<<<dim3(10112), 256, 0, stream>>>(
        h01,       t0w2b, out + 10002, 256, 384, 30000, 235, 7520,
        h01 + 256, t1w2b, out + 40002, 64,  384, 10257, 81,
        in0, in1, cnts);
    gemm_tails_kernel<<<dim3(10112), 256, 0, stream>>>(
        h01,       t0w2b, out + 10002, 256, 384, 30000, 235, 7520,
        h01 + 256, t1w2b, out + 40002, 64,  384, 10257, 81,
        in0, in1, cnts);
}

// Round 14
// 470.002 us; speedup vs baseline: 1.0297x; 1.0297x over previous
//
#include <hip/hip_runtime.h>
#include <hip/hip_bf16.h>
#include <stdint.h>

// ---------------------------------------------------------------------------
// FacebookAdaptiveSoftmax forward on MI355X (gfx950) — R14
//   out[4096, 50259] = concat(x@head_w^T, (x@t0w1^T)@t0w2^T * m0, (x@t1w1^T)@t1w2^T * m1)
//   new_head_target[4096] appended flat (as float)
// R14 = R11 with ONE change (informed by R13's measurement: L2 ~= 160us,
// L3 ~= 142us): the 1568 one-shot fill blocks (each pinning a CU slot at
// 1 block/CU while BW-bound -> head compute starved to ~1/3 of the chip)
// are replaced by 96 PERSISTENT grid-stride fill blocks (ids == 3 mod 8,
// grid 768). 96 CUs saturate the spare write BW; 672/768 slots stay on
// head/h01 compute. L3 single launch (R13's duplicate removed).
// ---------------------------------------------------------------------------

typedef float  f32x4   __attribute__((ext_vector_type(4)));
typedef short  short8  __attribute__((ext_vector_type(8)));
typedef unsigned short ushort8 __attribute__((ext_vector_type(8)));

#define CUT0 10000
#define CUT1 40000
#define CUT2 50257
#define LDC   50259L

__device__ __forceinline__ void gload16(const void* g, void* l) {
    __builtin_amdgcn_global_load_lds(
        (__attribute__((address_space(1))) void*)(g),
        (__attribute__((address_space(3))) void*)(l), 16, 0, 0);
}

__device__ __forceinline__ unsigned short f2bf(float f) {
    unsigned int u = __float_as_uint(f);
    u += 0x7fffu + ((u >> 16) & 1u);   // round-to-nearest-even
    return (unsigned short)(u >> 16);
}

__device__ __forceinline__ short8 dsr128(unsigned addr) {
    f32x4 r;
    asm volatile("ds_read_b128 %0, %1" : "=v"(r) : "v"(addr));
    return __builtin_bit_cast(short8, r);
}

__device__ __forceinline__ f32x4 mfma16(short8 a, short8 b, f32x4 c) {
    return __builtin_amdgcn_mfma_f32_16x16x32_bf16(a, b, c, 0, 0, 0);
}

__device__ __forceinline__ void nt4(float* p, f32x4 v) {
    __builtin_nontemporal_store(v[0], p);
    __builtin_nontemporal_store(v[1], p + 1);
    __builtin_nontemporal_store(v[2], p + 2);
    __builtin_nontemporal_store(v[3], p + 3);
}

// ===========================================================================
// L0: target remap + order-preserving compaction scan (1 block, 1024 thr).
// ===========================================================================
__global__ __launch_bounds__(1024)
void scan_kernel(const int* __restrict__ tgt, float* __restrict__ outT,
                 int* __restrict__ in0, int* __restrict__ z0,
                 int* __restrict__ in1, int* __restrict__ z1,
                 int* __restrict__ cnts) {
    __shared__ int w0[16], w1[16];
    const int t = threadIdx.x;
    int f0[4], f1[4];
    int c0 = 0, c1 = 0;
#pragma unroll
    for (int j = 0; j < 4; ++j) {
        const int r = t * 4 + j;
        const int v = tgt[r];
        const int b0 = (v >= CUT0) && (v < CUT1);
        const int b1 = (v >= CUT1) && (v < CUT2);
        f0[j] = b0; f1[j] = b1;
        c0 += b0; c1 += b1;
        outT[r] = (float)(b0 ? CUT0 : (b1 ? CUT0 + 1 : v));
    }
    const int lane = t & 63, w = t >> 6;
    int s0 = c0, s1 = c1;
    for (int d = 1; d < 64; d <<= 1) {
        const int u0 = __shfl_up(s0, d, 64);
        const int u1 = __shfl_up(s1, d, 64);
        if (lane >= d) { s0 += u0; s1 += u1; }
    }
    if (lane == 63) { w0[w] = s0; w1[w] = s1; }
    __syncthreads();
    if (t == 0) {
        int a0 = 0, a1 = 0;
        for (int i = 0; i < 16; ++i) {
            const int x0 = w0[i]; w0[i] = a0; a0 += x0;
            const int x1 = w1[i]; w1[i] = a1; a1 += x1;
        }
        cnts[0] = a0; cnts[1] = a1;
    }
    __syncthreads();
    int run0 = w0[w] + (s0 - c0);
    int run1 = w1[w] + (s1 - c1);
#pragma unroll
    for (int j = 0; j < 4; ++j) {
        const int r = t * 4 + j;
        if (f0[j]) in0[run0++] = r; else z0[r - run0] = r;
        if (f1[j]) in1[run1++] = r; else z1[r - run1] = r;
    }
}

// ===========================================================================
// L1: fused casts (5 segments, f32 -> bf16, zero row padding).
// ===========================================================================
struct CastSeg {
    const float* srcA;
    const float* srcB;
    unsigned short* dst;
    long rowsA, rowsB, total8;
    int lk, pad;
};
struct CastArgs {
    CastSeg s[5];
    long grand8;
};

__global__ __launch_bounds__(256)
void cast_kernel(CastArgs a) {
    long i = blockIdx.x * 256L + threadIdx.x;
    const long stride = (long)gridDim.x * 256L;
    for (; i < a.grand8; i += stride) {
        long off = i;
        int s = 0;
        while (s < 4 && off >= a.s[s].total8) { off -= a.s[s].total8; s++; }
        const CastSeg& sg = a.s[s];
        const long e   = off << 3;
        const long row = e >> sg.lk;
        ushort8 o;
        const float* src = nullptr;
        long r2 = row;
        if (row < sg.rowsA)      src = sg.srcA;
        else if (row < sg.rowsB) { src = sg.srcB; r2 = row - sg.rowsA; }
        if (src) {
            const long col = e & ((1L << sg.lk) - 1);
            const float* p = src + (r2 << sg.lk) + col;
            const float4 v0 = *(const float4*)(p);
            const float4 v1 = *(const float4*)(p + 4);
            o[0] = f2bf(v0.x); o[1] = f2bf(v0.y); o[2] = f2bf(v0.z); o[3] = f2bf(v0.w);
            o[4] = f2bf(v1.x); o[5] = f2bf(v1.y); o[6] = f2bf(v1.z); o[7] = f2bf(v1.w);
        } else {
            o = (ushort8)0;
        }
        *(ushort8*)(sg.dst + e) = o;
    }
}

// ===========================================================================
// L2: 8-phase 256x256 BK=64 GEMM (head f32-out | h01 bf16-out) + 96
// PERSISTENT grid-stride fill blocks (ids == 3 mod 8; NT stores).
// Grid 768: fill if (id&7)==3 (96 blocks, fidx = id>>3, stride 96 over the
// combined z0|z1 row list); else GEMM gid = id - ((id+5)>>3) in [0,672).
// ===========================================================================
#define STAGE2(MATP, LDM, RB, KCOL, LOFF)                                          \
    do {                                                                           \
        const unsigned short* _s0 = (MATP) + ((long)((RB) + (tid >> 3))) * (LDM) + (KCOL); \
        gload16(_s0, smem + (LOFF) + wave * 1024);                                 \
        const unsigned short* _s1 = (MATP) + ((long)((RB) + 64 + (tid >> 3))) * (LDM) + (KCOL); \
        gload16(_s1, smem + (LOFF) + 8192 + wave * 1024);                          \
    } while (0)

__global__ __launch_bounds__(512, 2)
void gemm8_dual_kernel(const unsigned short* __restrict__ A0,
                       const unsigned short* __restrict__ B0,
                       float* __restrict__ C0,
                       int nkt0, int lda0, int ldb0, int width0, int NB0, int nblk0,
                       const unsigned short* __restrict__ A1,
                       const unsigned short* __restrict__ B1,
                       unsigned short* __restrict__ C1,
                       int nkt1, int lda1, int ldb1, long ldc1, int width1, int NB1,
                       const int* __restrict__ z0, const int* __restrict__ z1,
                       const int* __restrict__ cnts, float* __restrict__ outFull) {
    __shared__ char smem[131072];

    const int tid  = threadIdx.x;
    const int lane = tid & 63;
    const int wave = tid >> 6;
    const int wr   = wave >> 2;
    const int wc   = wave & 3;

    // ---- id -> {persistent fill | GEMM gid} ----
    const int id = blockIdx.x;
    if ((id & 7) == 3) {
        // persistent fill block: grid-stride over combined z0|z1 rows
        const int fidx = id >> 3;                // 0..95
        const int zc0 = 4096 - cnts[0];
        const int zc1 = 4096 - cnts[1];
        const int zc  = zc0 + zc1;
        const f32x4 zv = {0.f, 0.f, 0.f, 0.f};
        for (int s = fidx; s < zc; s += 96) {
            const bool isT0 = s < zc0;
            const int rr = isT0 ? z0[s] : z1[s - zc0];
            float* base = outFull + (long)rr * LDC + (isT0 ? 10002 : 40002);
            const int width = isT0 ? 30000 : 10257;
            for (int j = tid * 4; j + 3 < width; j += 2048)
                nt4(base + j, zv);
            for (int j = (width & ~3) + tid; j < width; j += 512)
                __builtin_nontemporal_store(0.f, base + j);
        }
        return;
    }
    const int gid = id - ((id + 5) >> 3);        // 0..671

    const bool isHead = gid < nblk0;
    const unsigned short* A = isHead ? A0 : A1;
    const unsigned short* B = isHead ? B0 : B1;
    const int nkt   = isHead ? nkt0 : nkt1;
    const int lda   = isHead ? lda0 : lda1;
    const int ldb   = isHead ? ldb0 : ldb1;
    const int width = isHead ? width0 : width1;
    const int NB    = isHead ? NB0 : NB1;
    const int lbid  = isHead ? gid : gid - nblk0;
    const int nwg   = isHead ? nblk0 : 672 - nblk0;

    const int q = nwg >> 3, r = nwg & 7;
    const int xcd = lbid & 7, loc = lbid >> 3;
    const int L = (xcd < r ? xcd * (q + 1) : r * (q + 1) + (xcd - r) * q) + loc;
    const int g = L / (NB * 4);
    const int t = L - g * (NB * 4);
    const long bm = g * 4 + (t & 3);
    const long bn = t >> 2;

    const long bmRow = bm * 256;
    const long bnRow = bn * 256;

    const int scol = (((tid & 7) ^ ((tid >> 3) & 7)) << 3);

    const unsigned lane15 = lane & 15;
    const unsigned rsw   = (lane15 & 7) << 4;
    const unsigned kcol0 = (((lane >> 4) << 4)) ^ rsw;
    const unsigned kcol1 = (64u + ((lane >> 4) << 4)) ^ rsw;
    const unsigned smemBase =
        (unsigned)(size_t)(__attribute__((address_space(3))) char*)smem;
    const unsigned aB0 = smemBase + wr * 16384 + lane15 * 128;
    const unsigned bB0 = smemBase + 32768 + (wc >> 1) * 16384 +
                         ((wc & 1) * 64 + lane15) * 128;

    f32x4 acc[8][4];
#pragma unroll
    for (int m = 0; m < 8; m++)
#pragma unroll
        for (int n = 0; n < 4; n++) acc[m][n] = (f32x4){0.f, 0.f, 0.f, 0.f};

    STAGE2(A, lda, bmRow,       scol, 0);
    STAGE2(A, lda, bmRow + 128, scol, 16384);
    STAGE2(B, ldb, bnRow,       scol, 32768);
    STAGE2(B, ldb, bnRow + 128, scol, 49152);

    short8 afk0[4], afk1[4], bA0[2], bA1[2], bH0[2], bH1[2];

    for (int kt = 0; kt < nkt; ++kt) {
        const int c  = kt & 1;
        const bool pf = (kt + 1) < nkt;
        const int kc = (kt + 1) * 64 + scol;
        const unsigned aBase = aB0 + c * 65536;
        const unsigned bBase = bB0 + c * 65536;
        const unsigned lOff  = (c ^ 1) * 65536;

        // phase 0 : Q0
        if (pf) {
            STAGE2(A, lda, bmRow, kc, lOff);
            asm volatile("s_waitcnt vmcnt(2)" ::: "memory");
        } else {
            asm volatile("s_waitcnt vmcnt(0)" ::: "memory");
        }
        __builtin_amdgcn_s_barrier();
#pragma unroll
        for (int mf = 0; mf < 4; ++mf) {
            afk0[mf] = dsr128(aBase + mf * 2048 + kcol0);
            afk1[mf] = dsr128(aBase + mf * 2048 + kcol1);
        }
#pragma unroll
        for (int nf = 0; nf < 2; ++nf) {
            bA0[nf] = dsr128(bBase + nf * 2048 + kcol0);
            bA1[nf] = dsr128(bBase + nf * 2048 + kcol1);
        }
        asm volatile("s_waitcnt lgkmcnt(0)" ::: "memory");
        __builtin_amdgcn_sched_barrier(0);
        __builtin_amdgcn_s_setprio(1);
#pragma unroll
        for (int mf = 0; mf < 4; ++mf)
#pragma unroll
            for (int nf = 0; nf < 2; ++nf) {
                acc[mf][nf] = mfma16(bA0[nf], afk0[mf], acc[mf][nf]);
                acc[mf][nf] = mfma16(bA1[nf], afk1[mf], acc[mf][nf]);
            }
        __builtin_amdgcn_s_setprio(0);
        __builtin_amdgcn_s_barrier();

        // phase 1 : Q1
#pragma unroll
        for (int nf = 0; nf < 2; ++nf) {
            bH0[nf] = dsr128(bBase + (2 + nf) * 2048 + kcol0);
            bH1[nf] = dsr128(bBase + (2 + nf) * 2048 + kcol1);
        }
        if (pf) STAGE2(A, lda, bmRow + 128, kc, lOff + 16384);
        __builtin_amdgcn_s_barrier();
        asm volatile("s_waitcnt lgkmcnt(0)" ::: "memory");
        __builtin_amdgcn_sched_barrier(0);
        __builtin_amdgcn_s_setprio(1);
#pragma unroll
        for (int mf = 0; mf < 4; ++mf)
#pragma unroll
            for (int nf = 0; nf < 2; ++nf) {
                acc[mf][2 + nf] = mfma16(bH0[nf], afk0[mf], acc[mf][2 + nf]);
                acc[mf][2 + nf] = mfma16(bH1[nf], afk1[mf], acc[mf][2 + nf]);
            }
        __builtin_amdgcn_s_setprio(0);
        __builtin_amdgcn_s_barrier();

        // phase 2 : Q2
#pragma unroll
        for (int mf = 0; mf < 4; ++mf) {
            afk0[mf] = dsr128(aBase + (4 + mf) * 2048 + kcol0);
            afk1[mf] = dsr128(aBase + (4 + mf) * 2048 + kcol1);
        }
        if (pf) STAGE2(B, ldb, bnRow, kc, lOff + 32768);
        __builtin_amdgcn_s_barrier();
        asm volatile("s_waitcnt lgkmcnt(0)" ::: "memory");
        __builtin_amdgcn_sched_barrier(0);
        __builtin_amdgcn_s_setprio(1);
#pragma unroll
        for (int mf = 0; mf < 4; ++mf)
#pragma unroll
            for (int nf = 0; nf < 2; ++nf) {
                acc[4 + mf][2 + nf] = mfma16(bH0[nf], afk0[mf], acc[4 + mf][2 + nf]);
                acc[4 + mf][2 + nf] = mfma16(bH1[nf], afk1[mf], acc[4 + mf][2 + nf]);
            }
        __builtin_amdgcn_s_setprio(0);
        __builtin_amdgcn_s_barrier();

        // phase 3 : Q3
#pragma unroll
        for (int nf = 0; nf < 2; ++nf) {
            bA0[nf] = dsr128(bBase + nf * 2048 + kcol0);
            bA1[nf] = dsr128(bBase + nf * 2048 + kcol1);
        }
        if (pf) STAGE2(B, ldb, bnRow + 128, kc, lOff + 49152);
        __builtin_amdgcn_s_barrier();
        asm volatile("s_waitcnt lgkmcnt(0)" ::: "memory");
        __builtin_amdgcn_sched_barrier(0);
        __builtin_amdgcn_s_setprio(1);
#pragma unroll
        for (int mf = 0; mf < 4; ++mf)
#pragma unroll
            for (int nf = 0; nf < 2; ++nf) {
                acc[4 + mf][nf] = mfma16(bA0[nf], afk0[mf], acc[4 + mf][nf]);
                acc[4 + mf][nf] = mfma16(bA1[nf], afk1[mf], acc[4 + mf][nf]);
            }
        __builtin_amdgcn_s_setprio(0);
        __builtin_amdgcn_s_barrier();
    }

    const int cb4 = (lane >> 4) << 2;
    if (isHead) {
        // transposed coalesced epilogue: LDS [128][256] f32, 2 passes
        for (int h = 0; h < 2; ++h) {
            __syncthreads();
            if (wr == h) {
#pragma unroll
                for (int mf = 0; mf < 8; ++mf) {
                    const int rl = mf * 16 + (int)lane15;
#pragma unroll
                    for (int nf = 0; nf < 4; ++nf) {
                        const int slot = wc * 16 + nf * 4 + (lane >> 4);
                        const int sl = slot ^ (rl & 7);
                        *(f32x4*)(smem + rl * 1024 + sl * 16) = acc[mf][nf];
                    }
                }
            }
            __syncthreads();
            const int colBase = (int)bnRow + lane * 4;
#pragma unroll
            for (int it = 0; it < 16; ++it) {
                const int rl = wave * 16 + it;
                const int sl = lane ^ (rl & 7);
                const f32x4 v = *(const f32x4*)(smem + rl * 1024 + sl * 16);
                float* rp = C0 + (bmRow + h * 128 + rl) * LDC;
                if (colBase + 3 < width) {
                    __builtin_memcpy(rp + colBase, &v, 16);
                } else {
#pragma unroll
                    for (int j = 0; j < 4; ++j)
                        if (colBase + j < width) rp[colBase + j] = v[j];
                }
            }
        }
    } else {
#pragma unroll
        for (int mf = 0; mf < 8; ++mf) {
            const long grow = bmRow + wr * 128 + mf * 16 + lane15;
            unsigned short* rp = C1 + grow * ldc1;
#pragma unroll
            for (int nf = 0; nf < 4; ++nf) {
                const int gcb = (int)bnRow + wc * 64 + nf * 16 + cb4;
                const f32x4 v = acc[mf][nf];
                ushort4 o;
                o.x = f2bf(v[0]); o.y = f2bf(v[1]); o.z = f2bf(v[2]); o.w = f2bf(v[3]);
                if (gcb + 3 < width) {
                    *(ushort4*)(rp + gcb) = o;
                } else {
                    unsigned short tmp[4] = {o.x, o.y, o.z, o.w};
#pragma unroll
                    for (int j = 0; j < 4; ++j)
                        if (gcb + j < width) rp[gcb + j] = tmp[j];
                }
            }
        }
    }
}

// ===========================================================================
// L3: compacted tails, BK=64, rule-21 swizzled staging/reads, transposed
// coalesced epilogue with NT scalar stores. (R11 verbatim.)
// ===========================================================================
__global__ __launch_bounds__(256)
void gemm_tails_kernel(const unsigned short* __restrict__ A0,
                       const unsigned short* __restrict__ B0,
                       float* __restrict__ C0,
                       int K0, int lda0, int width0, int NB0, int nblk0,
                       const unsigned short* __restrict__ A1,
                       const unsigned short* __restrict__ B1,
                       float* __restrict__ C1,
                       int K1, int lda1, int width1, int NB1,
                       const int* __restrict__ in0,
                       const int* __restrict__ in1,
                       const int* __restrict__ cnts) {
    __shared__ char tsm[32768];

    const int tid  = threadIdx.x;
    const int lane = tid & 63;
    const int wave = tid >> 6;
    const int wr   = wave >> 1;
    const int wc   = wave & 1;

    const bool is0 = (int)blockIdx.x < nblk0;
    const unsigned short* A = is0 ? A0 : A1;
    const unsigned short* B = is0 ? B0 : B1;
    float* Cf               = is0 ? C0 : C1;
    const int* rowlist      = is0 ? in0 : in1;
    const int cnt           = cnts[is0 ? 0 : 1];
    const int K     = is0 ? K0 : K1;
    const int lda   = is0 ? lda0 : lda1;
    const int width = is0 ? width0 : width1;
    const int NB    = is0 ? NB0 : NB1;
    const int lbid  = is0 ? blockIdx.x : blockIdx.x - nblk0;
    const int nwg   = is0 ? nblk0 : (int)gridDim.x - nblk0;

    const int q = nwg >> 3, r = nwg & 7;
    const int xcd = lbid & 7, loc = lbid >> 3;
    const int L = (xcd < r ? xcd * (q + 1) : r * (q + 1) + (xcd - r) * q) + loc;
    const int g = L / (NB << 3);
    const int t = L - g * (NB << 3);
    const long bm = (g << 3) + (t & 7);
    const long bn = t >> 3;

    if ((int)(bm * 128) >= cnt) return;

    const int cm1 = cnt - 1;
    const int s_row = tid >> 3;                          // 0..31
    const int sc    = (((tid & 7) ^ (s_row & 7)) << 3);  // elem col

    int ar[4];
#pragma unroll
    for (int gg = 0; gg < 4; ++gg) {
        const int gi = (int)(bm * 128) + s_row + 32 * gg;
        ar[gg] = rowlist[gi < cnt ? gi : cm1];
    }
    const unsigned short* pB0 = B + (bn * 128 + s_row) * (long)K + sc;

    f32x4 acc[4][4];
#pragma unroll
    for (int m = 0; m < 4; m++)
#pragma unroll
        for (int n = 0; n < 4; n++) acc[m][n] = (f32x4){0.f, 0.f, 0.f, 0.f};

    const int f_r = lane & 15;
    const int fkb = (lane >> 4) << 4;   // byte offset of k-chunk in half

    for (int k0 = 0; k0 < K; k0 += 64) {
#pragma unroll
        for (int gg = 0; gg < 4; ++gg) {
            gload16(A + (long)ar[gg] * lda + sc + k0,
                    tsm + gg * 4096 + wave * 1024);
            gload16(pB0 + (long)(32 * gg) * K + k0,
                    tsm + 16384 + gg * 4096 + wave * 1024);
        }
        __syncthreads();

#pragma unroll
        for (int h = 0; h < 2; ++h) {
            short8 af[4], bfr[4];
#pragma unroll
            for (int m = 0; m < 4; m++) {
                const int row = wr * 64 + m * 16 + f_r;
                const int cb = (h * 64 + fkb) ^ ((row & 7) << 4);
                af[m] = *(const short8*)(tsm + row * 128 + cb);
            }
#pragma unroll
            for (int n = 0; n < 4; n++) {
                const int row = wc * 64 + n * 16 + f_r;
                const int cb = (h * 64 + fkb) ^ ((row & 7) << 4);
                bfr[n] = *(const short8*)(tsm + 16384 + row * 128 + cb);
            }
#pragma unroll
            for (int m = 0; m < 4; m++)
#pragma unroll
                for (int n = 0; n < 4; n++)
                    acc[m][n] = mfma16(bfr[n], af[m], acc[m][n]);
        }
        __syncthreads();
    }

    // ---- transposed coalesced epilogue: LDS [64][128] f32, 2 passes ----
    const int c_a  = lane & 15;
    const int colL = (lane & 31) * 4;
    for (int h = 0; h < 2; ++h) {
        __syncthreads();
        if (wr == h) {
#pragma unroll
            for (int m = 0; m < 4; ++m) {
                const int rl = m * 16 + c_a;
#pragma unroll
                for (int n = 0; n < 4; ++n) {
                    const int slot = wc * 16 + n * 4 + (lane >> 4);
                    const int sl = slot ^ (rl & 7);
                    *(f32x4*)(tsm + rl * 512 + sl * 16) = acc[m][n];
                }
            }
        }
        __syncthreads();
#pragma unroll
        for (int it = 0; it < 8; ++it) {
            const int rl = wave * 16 + it * 2 + (lane >> 5);
            const int gri = (int)(bm * 128) + h * 64 + rl;
            if (gri < cnt) {
                const int sl = (lane & 31) ^ (rl & 7);
                const f32x4 v = *(const f32x4*)(tsm + rl * 512 + sl * 16);
                const long orow = rowlist[gri];
                float* rp = Cf + orow * LDC;
                const int col = (int)(bn * 128) + colL;
                if (col + 3 < width) {
                    nt4(rp + col, v);
                } else {
#pragma unroll
                    for (int j = 0; j < 4; ++j)
                        if (col + j < width)
                            __builtin_nontemporal_store(v[j], rp + col + j);
                }
            }
        }
    }
}

extern "C" void kernel_launch(void* const* d_in, const int* in_sizes, int n_in,
                              void* d_out, int out_size, void* d_ws, size_t ws_size,
                              hipStream_t stream) {
    const float* x      = (const float*)d_in[0];   // [4096,1024]
    const int*   target = (const int*)  d_in[1];   // [4096]
    const float* head_w = (const float*)d_in[2];   // [10002,1024]
    const float* t0_w1  = (const float*)d_in[3];   // [256,1024]
    const float* t0_w2  = (const float*)d_in[4];   // [30000,256]
    const float* t1_w1  = (const float*)d_in[5];   // [64,1024]
    const float* t1_w2  = (const float*)d_in[6];   // [10257,64]
    float* out = (float*)d_out;

    // ---- ws layout (bytes) ----
    char* ws = (char*)d_ws;
    unsigned short* xb    = (unsigned short*)(ws + 0);          // 4096x1024
    unsigned short* hwb   = (unsigned short*)(ws + 8388608);    // 10240x1024
    unsigned short* w01b  = (unsigned short*)(ws + 29360128);   // 512x1024 (t0w1|t1w1|0)
    unsigned short* t0w2b = (unsigned short*)(ws + 30408704);   // 30208x256
    unsigned short* t1w2b = (unsigned short*)(ws + 45875200);   // 10496x64
    unsigned short* h01   = (unsigned short*)(ws + 47218688);   // 4096x384 bf16
    int*            in0   = (int*)(ws + 50364416);              // 4096
    int*            z0l   = (int*)(ws + 50380800);              // 4096
    int*            in1   = (int*)(ws + 50397184);              // 4096
    int*            z1l   = (int*)(ws + 50413568);              // 4096
    int*            cnts  = (int*)(ws + 50429952);              // 2

    // ---- L0: scan (target remap + compaction lists) ----
    scan_kernel<<<1, 1024, 0, stream>>>(target, out + 4096L * LDC,
                                        in0, z0l, in1, z1l, cnts);

    // ---- L1: casts ----
    CastArgs ca;
    ca.s[0] = {x,      nullptr, xb,    4096,  4096,  524288,  10, 0};
    ca.s[1] = {head_w, nullptr, hwb,   10002, 10002, 1310720, 10, 0};
    ca.s[2] = {t0_w1,  t1_w1,   w01b,  256,   320,   65536,   10, 0};
    ca.s[3] = {t0_w2,  nullptr, t0w2b, 30000, 30000, 966656,  8,  0};
    ca.s[4] = {t1_w2,  nullptr, t1w2b, 10257, 10257, 83968,   6,  0};
    ca.grand8 = 524288 + 1310720 + 65536 + 966656 + 83968;  // 2951168
    cast_kernel<<<2048, 256, 0, stream>>>(ca);

    // ---- L2: head (640) + h01 (32) GEMM blocks + 96 persistent fill
    //          blocks (ids == 3 mod 8), grid 768 ----
    gemm8_dual_kernel<<<dim3(768), 512, 0, stream>>>(
        xb, hwb, out, 16, 1024, 1024, 10002, 40, 640,
        xb, w01b, h01, 16, 1024, 1024, 384L, 384, 2,
        z0l, z1l, cnts, out);

    // ---- L3: compacted tails (BK=64) ----
    gemm_tails_kernel<<<dim3(10112), 256, 0, stream>>>(
        h01,       t0w2b, out + 10002, 256, 384, 30000, 235, 7520,
        h01 + 256, t1w2b, out + 40002, 64,  384, 10257, 81,
        in0, in1, cnts);
}

// Round 15
// 330.153 us; speedup vs baseline: 1.4658x; 1.4236x over previous
//
#include <hip/hip_runtime.h>
#include <hip/hip_bf16.h>
#include <stdint.h>

// ---------------------------------------------------------------------------
// FacebookAdaptiveSoftmax forward on MI355X (gfx950) — R15
//   out[4096, 50259] = concat(x@head_w^T, (x@t0w1^T)@t0w2^T * m0, (x@t1w1^T)@t1w2^T * m1)
//   new_head_target[4096] appended flat (as float)
// R15 (base R11; R12-R14 experiments reverted): merge the write-heavy tails
// into the compute-heavy head launch (R11's proven writers+computers mixing,
// applied maximally). Enabled by computing h01 in L1 from RAW f32 inputs
// (reg-staged cast m97 block) so tails have no dependency on L2 itself.
//   L0: scan. L1: 96 h01 blocks + casts. L2 (mega): 640 head 8-phase +
//   1888 tail0 (nkt=4, gather/scatter) + 656 tail1 (nkt=1) + strided fills,
//   period-5 interleave. L3 deleted.
// ---------------------------------------------------------------------------

typedef float  f32x4   __attribute__((ext_vector_type(4)));
typedef short  short8  __attribute__((ext_vector_type(8)));
typedef unsigned short ushort8 __attribute__((ext_vector_type(8)));

#define CUT0 10000
#define CUT1 40000
#define CUT2 50257
#define LDC   50259L

__device__ __forceinline__ void gload16(const void* g, void* l) {
    __builtin_amdgcn_global_load_lds(
        (__attribute__((address_space(1))) void*)(g),
        (__attribute__((address_space(3))) void*)(l), 16, 0, 0);
}

__device__ __forceinline__ unsigned short f2bf(float f) {
    unsigned int u = __float_as_uint(f);
    u += 0x7fffu + ((u >> 16) & 1u);   // round-to-nearest-even
    return (unsigned short)(u >> 16);
}

__device__ __forceinline__ short8 dsr128(unsigned addr) {
    f32x4 r;
    asm volatile("ds_read_b128 %0, %1" : "=v"(r) : "v"(addr));
    return __builtin_bit_cast(short8, r);
}

__device__ __forceinline__ f32x4 mfma16(short8 a, short8 b, f32x4 c) {
    return __builtin_amdgcn_mfma_f32_16x16x32_bf16(a, b, c, 0, 0, 0);
}

__device__ __forceinline__ void nt4(float* p, f32x4 v) {
    __builtin_nontemporal_store(v[0], p);
    __builtin_nontemporal_store(v[1], p + 1);
    __builtin_nontemporal_store(v[2], p + 2);
    __builtin_nontemporal_store(v[3], p + 3);
}

__device__ __forceinline__ ushort8 cvt8(const float* p) {
    const float4 v0 = *(const float4*)p;
    const float4 v1 = *(const float4*)(p + 4);
    ushort8 o;
    o[0] = f2bf(v0.x); o[1] = f2bf(v0.y); o[2] = f2bf(v0.z); o[3] = f2bf(v0.w);
    o[4] = f2bf(v1.x); o[5] = f2bf(v1.y); o[6] = f2bf(v1.z); o[7] = f2bf(v1.w);
    return o;
}

// ===========================================================================
// L0: target remap + order-preserving compaction scan (1 block, 1024 thr).
// ===========================================================================
__global__ __launch_bounds__(1024)
void scan_kernel(const int* __restrict__ tgt, float* __restrict__ outT,
                 int* __restrict__ in0, int* __restrict__ z0,
                 int* __restrict__ in1, int* __restrict__ z1,
                 int* __restrict__ cnts) {
    __shared__ int w0[16], w1[16];
    const int t = threadIdx.x;
    int f0[4], f1[4];
    int c0 = 0, c1 = 0;
#pragma unroll
    for (int j = 0; j < 4; ++j) {
        const int r = t * 4 + j;
        const int v = tgt[r];
        const int b0 = (v >= CUT0) && (v < CUT1);
        const int b1 = (v >= CUT1) && (v < CUT2);
        f0[j] = b0; f1[j] = b1;
        c0 += b0; c1 += b1;
        outT[r] = (float)(b0 ? CUT0 : (b1 ? CUT0 + 1 : v));
    }
    const int lane = t & 63, w = t >> 6;
    int s0 = c0, s1 = c1;
    for (int d = 1; d < 64; d <<= 1) {
        const int u0 = __shfl_up(s0, d, 64);
        const int u1 = __shfl_up(s1, d, 64);
        if (lane >= d) { s0 += u0; s1 += u1; }
    }
    if (lane == 63) { w0[w] = s0; w1[w] = s1; }
    __syncthreads();
    if (t == 0) {
        int a0 = 0, a1 = 0;
        for (int i = 0; i < 16; ++i) {
            const int x0 = w0[i]; w0[i] = a0; a0 += x0;
            const int x1 = w1[i]; w1[i] = a1; a1 += x1;
        }
        cnts[0] = a0; cnts[1] = a1;
    }
    __syncthreads();
    int run0 = w0[w] + (s0 - c0);
    int run1 = w1[w] + (s1 - c1);
#pragma unroll
    for (int j = 0; j < 4; ++j) {
        const int r = t * 4 + j;
        if (f0[j]) in0[run0++] = r; else z0[r - run0] = r;
        if (f1[j]) in1[run1++] = r; else z1[r - run1] = r;
    }
}

// ===========================================================================
// L1: blocks 0..95 = h01 GEMM (m97 128^2, reg-staged f32->bf16 from RAW
// x/t0w1/t1w1 -> h01 bf16 [4096,384]); blocks 96.. = fused casts (4 segs).
// ===========================================================================
struct CastSeg {
    const float* src;
    unsigned short* dst;
    long rows, total8;
    int lk, pad;
};
struct CastArgs {
    CastSeg s[4];
    long grand8;
};

__device__ __forceinline__ ushort8 wfetch(const float* t0w1, const float* t1w1,
                                          int row, int cidx) {
    if (row < 256) return cvt8(t0w1 + (long)row * 1024 + cidx);
    if (row < 320) return cvt8(t1w1 + (long)(row - 256) * 1024 + cidx);
    return (ushort8)0;
}

__global__ __launch_bounds__(256)
void cast_h01_kernel(CastArgs a, const float* __restrict__ x,
                     const float* __restrict__ t0w1,
                     const float* __restrict__ t1w1,
                     unsigned short* __restrict__ h01) {
    __shared__ unsigned short As[128 * 32];
    __shared__ unsigned short Bs[128 * 32];
    const int tid = threadIdx.x;

    if (blockIdx.x < 96) {
        // ---- h01 block: h01[4096,384] = bf16(x @ [t0w1;t1w1;0]^T) ----
        const int bid = blockIdx.x;
        const int bn = bid % 3, bm = bid / 3;       // 3 col-tiles x 32 row-tiles
        const int lane = tid & 63, wave = tid >> 6;
        const int wr = wave >> 1, wc = wave & 1;
        const int s_row = tid >> 2, s_col = (tid & 3) << 3;
        const int ra0 = bm * 128 + s_row, ra1 = ra0 + 64;
        const int rb0 = bn * 128 + s_row, rb1 = rb0 + 64;

        f32x4 acc[4][4];
#pragma unroll
        for (int m = 0; m < 4; m++)
#pragma unroll
            for (int n = 0; n < 4; n++) acc[m][n] = (f32x4){0.f, 0.f, 0.f, 0.f};

        const int f_r = lane & 15;
        const int f_k = (lane >> 4) << 3;

        for (int k0 = 0; k0 < 1024; k0 += 32) {
            const ushort8 av0 = cvt8(x + (long)ra0 * 1024 + k0 + s_col);
            const ushort8 av1 = cvt8(x + (long)ra1 * 1024 + k0 + s_col);
            const ushort8 bv0 = wfetch(t0w1, t1w1, rb0, k0 + s_col);
            const ushort8 bv1 = wfetch(t0w1, t1w1, rb1, k0 + s_col);
            *(ushort8*)((char*)As + tid * 16)        = av0;
            *(ushort8*)((char*)As + 4096 + tid * 16) = av1;
            *(ushort8*)((char*)Bs + tid * 16)        = bv0;
            *(ushort8*)((char*)Bs + 4096 + tid * 16) = bv1;
            __syncthreads();

            short8 af[4], bfr[4];
#pragma unroll
            for (int m = 0; m < 4; m++)
                af[m] = *(const short8*)&As[(wr * 64 + m * 16 + f_r) * 32 + f_k];
#pragma unroll
            for (int n = 0; n < 4; n++)
                bfr[n] = *(const short8*)&Bs[(wc * 64 + n * 16 + f_r) * 32 + f_k];
#pragma unroll
            for (int m = 0; m < 4; m++)
#pragma unroll
                for (int n = 0; n < 4; n++)
                    acc[m][n] = mfma16(bfr[n], af[m], acc[m][n]);
            __syncthreads();
        }

        const int c_a  = lane & 15;
        const int c_b4 = (lane >> 4) << 2;
#pragma unroll
        for (int m = 0; m < 4; m++) {
            const long grow = bm * 128 + wr * 64 + m * 16 + c_a;
            unsigned short* rp = h01 + grow * 384L;
#pragma unroll
            for (int n = 0; n < 4; n++) {
                const int gcb = bn * 128 + wc * 64 + n * 16 + c_b4;
                const f32x4 v = acc[m][n];
                ushort4 o;
                o.x = f2bf(v[0]); o.y = f2bf(v[1]); o.z = f2bf(v[2]); o.w = f2bf(v[3]);
                *(ushort4*)(rp + gcb) = o;
            }
        }
        return;
    }

    // ---- casts (grid-stride over 16B chunks; 4 segments) ----
    long i = (blockIdx.x - 96) * 256L + tid;
    const long stride = ((long)gridDim.x - 96) * 256L;
    for (; i < a.grand8; i += stride) {
        long off = i;
        int s = 0;
        while (s < 3 && off >= a.s[s].total8) { off -= a.s[s].total8; s++; }
        const CastSeg& sg = a.s[s];
        const long e   = off << 3;
        const long row = e >> sg.lk;
        ushort8 o;
        if (row < sg.rows) {
            o = cvt8(sg.src + e);
        } else {
            o = (ushort8)0;
        }
        *(ushort8*)(sg.dst + e) = o;
    }
}

// ===========================================================================
// L2 (mega): 8-phase 256x256 BK=64 GEMM, three configs + fills.
// Grid 3200 = 640 periods x 5: pos 1 = head (640); else fidx = pid*4+{...}:
//   fidx<1888 -> tail0 (nkt=4, gather in0/scatter, NT stores, fills z0)
//   fidx<2544 -> tail1 (nkt=1, gather in1/scatter, NT stores, fills z1)
//   else      -> idle spare (16)
// Head: rowlist null, plain stores, no fills. All R11 8-phase mechanics.
// ===========================================================================
struct G8 {
    const unsigned short* A;
    const unsigned short* B;
    float* C;                 // includes column offset
    const int* rowlist;       // null -> identity
    const int* zlist;         // null -> no fills
    int nkt, lda, ldb, width, NB, nwg, cntSel, pad;
};

#define STAGEA(HJ, KCOL, LOFF)                                                 \
    do {                                                                       \
        gload16(c.A + parow[2 * (HJ)] + (KCOL),     smem + (LOFF) + wave * 1024); \
        gload16(c.A + parow[2 * (HJ) + 1] + (KCOL), smem + (LOFF) + 8192 + wave * 1024); \
    } while (0)
#define STAGEB(RB, KCOL, LOFF)                                                 \
    do {                                                                       \
        gload16(c.B + ((long)((RB) + tr)) * c.ldb + (KCOL),      smem + (LOFF) + wave * 1024); \
        gload16(c.B + ((long)((RB) + 64 + tr)) * c.ldb + (KCOL), smem + (LOFF) + 8192 + wave * 1024); \
    } while (0)

__global__ __launch_bounds__(512, 2)
void mega_kernel(G8 hc, G8 t0c, G8 t1c, const int* __restrict__ cnts) {
    __shared__ char smem[131072];

    const int tid  = threadIdx.x;
    const int lane = tid & 63;
    const int wave = tid >> 6;
    const int wr   = wave >> 2;
    const int wc   = wave & 3;

    // ---- block type select (period-5 interleave) ----
    const int pid = blockIdx.x / 5;
    const int pos = blockIdx.x - 5 * pid;
    G8 c; int lbid;
    if (pos == 1) {
        c = hc; lbid = pid;
    } else {
        const int f = pid * 4 + (pos == 0 ? 0 : pos - 1);
        if (f < 1888)      { c = t0c; lbid = f; }
        else if (f < 2544) { c = t1c; lbid = f - 1888; }
        else return;       // 16 spare blocks
    }
    const int cnt = (c.cntSel < 0) ? 4096 : cnts[c.cntSel];

    // ---- bijective XCD chunk + GROUP_M=4 (nwg % 8 == 0: 640/1888/656) ----
    const int nwg = c.nwg, NB = c.NB;
    const int q = nwg >> 3, r = nwg & 7;
    const int xcd = lbid & 7, loc = lbid >> 3;
    const int L = (xcd < r ? xcd * (q + 1) : r * (q + 1) + (xcd - r) * q) + loc;
    const int g = L / (NB * 4);
    const int t = L - g * (NB * 4);
    const long bm = g * 4 + (t & 3);
    const long bn = t >> 2;

    const long bmRow = bm * 256;
    const long bnRow = bn * 256;

    const bool active = (int)bmRow < cnt;

    if (active) {
        const int tr = tid >> 3;                         // staging row 0..63
        const int scol = (((tid & 7) ^ (tr & 7)) << 3);  // pre-swizzled col

        // gathered A-row offsets (element offsets; rows fixed across kt)
        long parow[4];
#pragma unroll
        for (int j = 0; j < 4; ++j) {
            const int gi = (int)bmRow + j * 64 + tr;
            const int rr = c.rowlist ? c.rowlist[gi < cnt ? gi : cnt - 1] : gi;
            parow[j] = (long)rr * c.lda;
        }

        const unsigned lane15 = lane & 15;
        const unsigned rsw   = (lane15 & 7) << 4;
        const unsigned kcol0 = (((lane >> 4) << 4)) ^ rsw;
        const unsigned kcol1 = (64u + ((lane >> 4) << 4)) ^ rsw;
        const unsigned smemBase =
            (unsigned)(size_t)(__attribute__((address_space(3))) char*)smem;
        const unsigned aB0 = smemBase + wr * 16384 + lane15 * 128;
        const unsigned bB0 = smemBase + 32768 + (wc >> 1) * 16384 +
                             ((wc & 1) * 64 + lane15) * 128;

        f32x4 acc[8][4];
#pragma unroll
        for (int m = 0; m < 8; m++)
#pragma unroll
            for (int n = 0; n < 4; n++) acc[m][n] = (f32x4){0.f, 0.f, 0.f, 0.f};

        STAGEA(0, scol, 0);
        STAGEA(1, scol, 16384);
        STAGEB(bnRow, scol, 32768);
        STAGEB(bnRow + 128, scol, 49152);

        short8 afk0[4], afk1[4], bA0[2], bA1[2], bH0[2], bH1[2];
        const int nkt = c.nkt;

        for (int kt = 0; kt < nkt; ++kt) {
            const int cc = kt & 1;
            const bool pf = (kt + 1) < nkt;
            const int kc = (kt + 1) * 64 + scol;
            const unsigned aBase = aB0 + cc * 65536;
            const unsigned bBase = bB0 + cc * 65536;
            const unsigned lOff  = (cc ^ 1) * 65536;

            // phase 0 : Q0
            if (pf) {
                STAGEA(0, kc, lOff);
                asm volatile("s_waitcnt vmcnt(2)" ::: "memory");
            } else {
                asm volatile("s_waitcnt vmcnt(0)" ::: "memory");
            }
            __builtin_amdgcn_s_barrier();
#pragma unroll
            for (int mf = 0; mf < 4; ++mf) {
                afk0[mf] = dsr128(aBase + mf * 2048 + kcol0);
                afk1[mf] = dsr128(aBase + mf * 2048 + kcol1);
            }
#pragma unroll
            for (int nf = 0; nf < 2; ++nf) {
                bA0[nf] = dsr128(bBase + nf * 2048 + kcol0);
                bA1[nf] = dsr128(bBase + nf * 2048 + kcol1);
            }
            asm volatile("s_waitcnt lgkmcnt(0)" ::: "memory");
            __builtin_amdgcn_sched_barrier(0);
            __builtin_amdgcn_s_setprio(1);
#pragma unroll
            for (int mf = 0; mf < 4; ++mf)
#pragma unroll
                for (int nf = 0; nf < 2; ++nf) {
                    acc[mf][nf] = mfma16(bA0[nf], afk0[mf], acc[mf][nf]);
                    acc[mf][nf] = mfma16(bA1[nf], afk1[mf], acc[mf][nf]);
                }
            __builtin_amdgcn_s_setprio(0);
            __builtin_amdgcn_s_barrier();

            // phase 1 : Q1
#pragma unroll
            for (int nf = 0; nf < 2; ++nf) {
                bH0[nf] = dsr128(bBase + (2 + nf) * 2048 + kcol0);
                bH1[nf] = dsr128(bBase + (2 + nf) * 2048 + kcol1);
            }
            if (pf) STAGEA(1, kc, lOff + 16384);
            __builtin_amdgcn_s_barrier();
            asm volatile("s_waitcnt lgkmcnt(0)" ::: "memory");
            __builtin_amdgcn_sched_barrier(0);
            __builtin_amdgcn_s_setprio(1);
#pragma unroll
            for (int mf = 0; mf < 4; ++mf)
#pragma unroll
                for (int nf = 0; nf < 2; ++nf) {
                    acc[mf][2 + nf] = mfma16(bH0[nf], afk0[mf], acc[mf][2 + nf]);
                    acc[mf][2 + nf] = mfma16(bH1[nf], afk1[mf], acc[mf][2 + nf]);
                }
            __builtin_amdgcn_s_setprio(0);
            __builtin_amdgcn_s_barrier();

            // phase 2 : Q2
#pragma unroll
            for (int mf = 0; mf < 4; ++mf) {
                afk0[mf] = dsr128(aBase + (4 + mf) * 2048 + kcol0);
                afk1[mf] = dsr128(aBase + (4 + mf) * 2048 + kcol1);
            }
            if (pf) STAGEB(bnRow, kc, lOff + 32768);
            __builtin_amdgcn_s_barrier();
            asm volatile("s_waitcnt lgkmcnt(0)" ::: "memory");
            __builtin_amdgcn_sched_barrier(0);
            __builtin_amdgcn_s_setprio(1);
#pragma unroll
            for (int mf = 0; mf < 4; ++mf)
#pragma unroll
                for (int nf = 0; nf < 2; ++nf) {
                    acc[4 + mf][2 + nf] = mfma16(bH0[nf], afk0[mf], acc[4 + mf][2 + nf]);
                    acc[4 + mf][2 + nf] = mfma16(bH1[nf], afk1[mf], acc[4 + mf][2 + nf]);
                }
            __builtin_amdgcn_s_setprio(0);
            __builtin_amdgcn_s_barrier();

            // phase 3 : Q3
#pragma unroll
            for (int nf = 0; nf < 2; ++nf) {
                bA0[nf] = dsr128(bBase + nf * 2048 + kcol0);
                bA1[nf] = dsr128(bBase + nf * 2048 + kcol1);
            }
            if (pf) STAGEB(bnRow + 128, kc, lOff + 49152);
            __builtin_amdgcn_s_barrier();
            asm volatile("s_waitcnt lgkmcnt(0)" ::: "memory");
            __builtin_amdgcn_sched_barrier(0);
            __builtin_amdgcn_s_setprio(1);
#pragma unroll
            for (int mf = 0; mf < 4; ++mf)
#pragma unroll
                for (int nf = 0; nf < 2; ++nf) {
                    acc[4 + mf][nf] = mfma16(bA0[nf], afk0[mf], acc[4 + mf][nf]);
                    acc[4 + mf][nf] = mfma16(bA1[nf], afk1[mf], acc[4 + mf][nf]);
                }
            __builtin_amdgcn_s_setprio(0);
            __builtin_amdgcn_s_barrier();
        }

        // ---- transposed coalesced epilogue: LDS [128][256] f32, 2 passes ----
        const int colBase = (int)bnRow + lane * 4;
        for (int h = 0; h < 2; ++h) {
            __syncthreads();
            if (wr == h) {
#pragma unroll
                for (int mf = 0; mf < 8; ++mf) {
                    const int rl = mf * 16 + (int)lane15;
#pragma unroll
                    for (int nf = 0; nf < 4; ++nf) {
                        const int slot = wc * 16 + nf * 4 + (lane >> 4);
                        const int sl = slot ^ (rl & 7);
                        *(f32x4*)(smem + rl * 1024 + sl * 16) = acc[mf][nf];
                    }
                }
            }
            __syncthreads();
#pragma unroll
            for (int it = 0; it < 16; ++it) {
                const int rl = wave * 16 + it;
                const int gri = (int)bmRow + h * 128 + rl;
                if (c.rowlist && gri >= cnt) continue;
                const int sl = lane ^ (rl & 7);
                const f32x4 v = *(const f32x4*)(smem + rl * 1024 + sl * 16);
                const long orow = c.rowlist ? (long)c.rowlist[gri] : (long)gri;
                float* rp = c.C + orow * LDC;
                if (colBase + 3 < c.width) {
                    if (c.rowlist) nt4(rp + colBase, v);
                    else __builtin_memcpy(rp + colBase, &v, 16);
                } else {
#pragma unroll
                    for (int j = 0; j < 4; ++j)
                        if (colBase + j < c.width) {
                            if (c.rowlist)
                                __builtin_nontemporal_store(v[j], rp + colBase + j);
                            else
                                rp[colBase + j] = v[j];
                        }
                }
            }
        }
    }

    // ---- zero-fill share (tail blocks; fine-grained, NT stores) ----
    if (c.zlist) {
        const f32x4 zv = {0.f, 0.f, 0.f, 0.f};
        const int zc = 4096 - cnt;
        for (int s = lbid; s < zc; s += c.nwg) {
            const int rr = c.zlist[s];
            float* base = c.C + (long)rr * LDC;
            for (int j = tid * 4; j + 3 < c.width; j += 2048)
                nt4(base + j, zv);
            for (int j = (c.width & ~3) + tid; j < c.width; j += 512)
                __builtin_nontemporal_store(0.f, base + j);
        }
    }
}

extern "C" void kernel_launch(void* const* d_in, const int* in_sizes, int n_in,
                              void* d_out, int out_size, void* d_ws, size_t ws_size,
                              hipStream_t stream) {
    const float* x      = (const float*)d_in[0];   // [4096,1024]
    const int*   target = (const int*)  d_in[1];   // [4096]
    const float* head_w = (const float*)d_in[2];   // [10002,1024]
    const float* t0_w1  = (const float*)d_in[3];   // [256,1024]
    const float* t0_w2  = (const float*)d_in[4];   // [30000,256]
    const float* t1_w1  = (const float*)d_in[5];   // [64,1024]
    const float* t1_w2  = (const float*)d_in[6];   // [10257,64]
    float* out = (float*)d_out;

    // ---- ws layout (bytes) ----
    char* ws = (char*)d_ws;
    unsigned short* xb    = (unsigned short*)(ws + 0);          // 4096x1024
    unsigned short* hwb   = (unsigned short*)(ws + 8388608);    // 10240x1024
    unsigned short* t0w2b = (unsigned short*)(ws + 30408704);   // 30208x256
    unsigned short* t1w2b = (unsigned short*)(ws + 45875200);   // 10496x64
    unsigned short* h01   = (unsigned short*)(ws + 47218688);   // 4096x384 bf16
    int*            in0   = (int*)(ws + 50364416);              // 4096
    int*            z0l   = (int*)(ws + 50380800);              // 4096
    int*            in1   = (int*)(ws + 50397184);              // 4096
    int*            z1l   = (int*)(ws + 50413568);              // 4096
    int*            cnts  = (int*)(ws + 50429952);              // 2

    // ---- L0: scan (target remap + compaction lists) ----
    scan_kernel<<<1, 1024, 0, stream>>>(target, out + 4096L * LDC,
                                        in0, z0l, in1, z1l, cnts);

    // ---- L1: h01 (96 blocks, raw-f32 m97 GEMM) + casts (1952 blocks) ----
    CastArgs ca;
    ca.s[0] = {x,      xb,    4096,  524288,  10, 0};
    ca.s[1] = {head_w, hwb,   10002, 1310720, 10, 0};
    ca.s[2] = {t0_w2,  t0w2b, 30000, 966656,  8,  0};
    ca.s[3] = {t1_w2,  t1w2b, 10257, 83968,   6,  0};
    ca.grand8 = 524288 + 1310720 + 966656 + 83968;  // 2885632
    cast_h01_kernel<<<dim3(2048), 256, 0, stream>>>(ca, x, t0_w1, t1_w1, h01);

    // ---- L2 (mega): head + tail0 + tail1 + fills, one launch ----
    G8 hc, t0c, t1c;
    hc  = {xb,        hwb,   out,         nullptr, nullptr, 16, 1024, 1024, 10002, 40,  640,  -1, 0};
    t0c = {h01,       t0w2b, out + 10002, in0,     z0l,     4,  384,  256,  30000, 118, 1888, 0,  0};
    t1c = {h01 + 256, t1w2b, out + 40002, in1,     z1l,     1,  384,  64,   10257, 41,  656,  1,  0};
    mega_kernel<<<dim3(3200), 512, 0, stream>>>(hc, t0c, t1c, cnts);
}